// Round 14
// baseline (413.488 us; speedup 1.0000x reference)
//
#include <hip/hip_runtime.h>

#define NN 50000
#define NE 800000
#define NB 64
#define DIM 64
#define TM 128
#define EB 4096       // edges per bucketA block
#define NBLK_A 196    // ceil(NE/EB)
#define NBKT 392      // buckets of 128 nodes: (50000+127)/128 = 391 -> 392 covers via s>>7
#define BN 128        // nodes per bucket

typedef float vfloat4 __attribute__((ext_vector_type(4)));

// ws: ve[NN*DIM f32] | U1[NB*DIM f32] | bbuf[NBLK_A*EB] | blkoff[NBLK_A*(NBKT+1)]

// Pass A: per-block LDS counting-sort of 4096 edges by bucket (s>>7).
// Coalesced writes; NO global atomics. blocks 0..63 also premix U1.
__global__ __launch_bounds__(1024) void bucketA_k(const int* __restrict__ src,
                                                  int* __restrict__ bbuf,
                                                  int* __restrict__ blkoff,
                                                  const float* __restrict__ u,
                                                  const float* __restrict__ W1,
                                                  const float* __restrict__ b1,
                                                  float* __restrict__ U1) {
    __shared__ int hist[NBKT];
    __shared__ int cnt2[NBKT];
    __shared__ int off[NBKT + 1];
    __shared__ int sortedE[EB];

    const int tid = threadIdx.x;
    const int blk = blockIdx.x;

    for (int i = tid; i < NBKT; i += 1024) { hist[i] = 0; cnt2[i] = 0; }
    __syncthreads();

    const int e0 = (blk * 1024 + tid) * 4;
    const bool valid = (e0 < NE);
    int4 s4 = make_int4(0, 0, 0, 0);
    if (valid) s4 = ((const int4*)src)[e0 >> 2];
    const int bk0 = s4.x >> 7, bk1 = s4.y >> 7, bk2 = s4.z >> 7, bk3 = s4.w >> 7;

    if (valid) {
        atomicAdd(&hist[bk0], 1);
        atomicAdd(&hist[bk1], 1);
        atomicAdd(&hist[bk2], 1);
        atomicAdd(&hist[bk3], 1);
    }
    __syncthreads();

    // exclusive scan of hist[392] by wave 0: 8 buckets per lane
    if (tid < 64) {
        const int base = tid * 8;
        int a[8];
        int sum = 0;
        #pragma unroll
        for (int i = 0; i < 8; ++i) {
            a[i] = (base + i < NBKT) ? hist[base + i] : 0;
            sum += a[i];
        }
        int run = sum;
        #pragma unroll
        for (int m = 1; m < 64; m <<= 1) {
            int v = __shfl_up(run, m, 64);
            if (tid >= m) run += v;
        }
        int acc2 = run - sum;
        #pragma unroll
        for (int i = 0; i < 8; ++i) {
            if (base + i < NBKT) off[base + i] = acc2;
            acc2 += a[i];
        }
        if (tid == 63) off[NBKT] = run;   // block's edge count
    }
    __syncthreads();

    if (valid) {
        int r0 = off[bk0] + atomicAdd(&cnt2[bk0], 1); sortedE[r0] = e0 + 0;
        int r1 = off[bk1] + atomicAdd(&cnt2[bk1], 1); sortedE[r1] = e0 + 1;
        int r2 = off[bk2] + atomicAdd(&cnt2[bk2], 1); sortedE[r2] = e0 + 2;
        int r3 = off[bk3] + atomicAdd(&cnt2[bk3], 1); sortedE[r3] = e0 + 3;
    }
    __syncthreads();

    const int nE = min(EB, NE - blk * EB);
    for (int i = tid; i < nE; i += 1024)
        bbuf[blk * EB + i] = sortedE[i];
    for (int i = tid; i <= NBKT; i += 1024)
        blkoff[blk * (NBKT + 1) + i] = off[i];

    if (blk < NB && tid < DIM) {
        float a = b1[tid];
        const float* up = u + blk * DIM;
        #pragma unroll 8
        for (int k = 0; k < DIM; ++k)
            a = fmaf(up[k], W1[(2 * DIM + k) * DIM + tid], a);
        U1[blk * DIM + tid] = a;
    }
}

// Pass B FUSED with reduce: one block per 128-node bucket. Gather ea rows for
// all bucket edges, ds_add_f32-accumulate into LDS, write v_e directly.
// eids/deg never exist in HBM.
__global__ __launch_bounds__(1024) void aggB_k(const int* __restrict__ src,
                                               const int* __restrict__ bbuf,
                                               const int* __restrict__ blkoff,
                                               const vfloat4* __restrict__ ea4,
                                               float4* __restrict__ ve4) {
    __shared__ float accum[BN][66];   // padded: slots land on disjoint bank sets
    __shared__ int cnt[BN];
    __shared__ int lo_s[NBLK_A], hi_s[NBLK_A];
    __shared__ int segoff[NBLK_A + 1];

    const int b = blockIdx.x;
    const int tid = threadIdx.x;
    const int wave = tid >> 6, lane = tid & 63;
    const int slot = lane >> 4, chunk = lane & 15;

    for (int i = tid; i < BN * 66; i += 1024) ((float*)accum)[i] = 0.f;
    if (tid < BN) cnt[tid] = 0;
    if (tid < NBLK_A) {
        lo_s[tid] = blkoff[tid * (NBKT + 1) + b];
        hi_s[tid] = blkoff[tid * (NBKT + 1) + b + 1];
    }
    __syncthreads();

    // exclusive scan of 196 segment lengths by wave 0 (4 per lane)
    if (tid < 64) {
        const int base = tid * 4;
        int a0 = 0, a1 = 0, a2 = 0, a3 = 0;
        if (base < NBLK_A) {
            a0 = hi_s[base + 0] - lo_s[base + 0];
            a1 = hi_s[base + 1] - lo_s[base + 1];
            a2 = hi_s[base + 2] - lo_s[base + 2];
            a3 = hi_s[base + 3] - lo_s[base + 3];
        }
        const int sum = a0 + a1 + a2 + a3;
        int run = sum;
        #pragma unroll
        for (int m = 1; m < 64; m <<= 1) {
            int v = __shfl_up(run, m, 64);
            if (tid >= m) run += v;
        }
        const int excl = run - sum;
        if (base < NBLK_A) {
            segoff[base + 0] = excl;
            segoff[base + 1] = excl + a0;
            segoff[base + 2] = excl + a0 + a1;
            segoff[base + 3] = excl + a0 + a1 + a2;
        }
        if (tid == 63) segoff[NBLK_A] = run;
    }
    __syncthreads();

    const int total = segoff[NBLK_A];
    // 8 edges per wave-iteration (2 per slot) -> 8 ea rows in flight per wave
    for (int base = wave * 8; base < total; base += 16 * 8) {
        int e0 = -1, e1 = -1, s0 = 0, s1 = 0;
        {
            const int i = base + slot;
            if (i < total) {
                int lo2 = 0, hi2 = NBLK_A;
                while (lo2 + 1 < hi2) {
                    int mid = (lo2 + hi2) >> 1;
                    if (segoff[mid] <= i) lo2 = mid; else hi2 = mid;
                }
                e0 = bbuf[lo2 * EB + (i - segoff[lo2] + lo_s[lo2])];
                s0 = src[e0];
            }
        }
        {
            const int i = base + 4 + slot;
            if (i < total) {
                int lo2 = 0, hi2 = NBLK_A;
                while (lo2 + 1 < hi2) {
                    int mid = (lo2 + hi2) >> 1;
                    if (segoff[mid] <= i) lo2 = mid; else hi2 = mid;
                }
                e1 = bbuf[lo2 * EB + (i - segoff[lo2] + lo_s[lo2])];
                s1 = src[e1];
            }
        }
        vfloat4 v0 = {0.f, 0.f, 0.f, 0.f}, v1 = {0.f, 0.f, 0.f, 0.f};
        if (e0 >= 0) v0 = __builtin_nontemporal_load(&ea4[(size_t)e0 * 16 + chunk]);
        if (e1 >= 0) v1 = __builtin_nontemporal_load(&ea4[(size_t)e1 * 16 + chunk]);
        if (e0 >= 0) {
            const int nl = s0 & (BN - 1);
            atomicAdd(&accum[nl][chunk * 4 + 0], v0.x);
            atomicAdd(&accum[nl][chunk * 4 + 1], v0.y);
            atomicAdd(&accum[nl][chunk * 4 + 2], v0.z);
            atomicAdd(&accum[nl][chunk * 4 + 3], v0.w);
            if (chunk == 0) atomicAdd(&cnt[nl], 1);
        }
        if (e1 >= 0) {
            const int nl = s1 & (BN - 1);
            atomicAdd(&accum[nl][chunk * 4 + 0], v1.x);
            atomicAdd(&accum[nl][chunk * 4 + 1], v1.y);
            atomicAdd(&accum[nl][chunk * 4 + 2], v1.z);
            atomicAdd(&accum[nl][chunk * 4 + 3], v1.w);
            if (chunk == 0) atomicAdd(&cnt[nl], 1);
        }
    }
    __syncthreads();

    // write v_e (divided) coalesced
    for (int i = tid; i < BN * 16; i += 1024) {
        const int nl = i >> 4, ch = i & 15;
        const int n = b * BN + nl;
        if (n < NN) {
            const float rs = 1.0f / fmaxf((float)cnt[nl], 1.0f);
            float4 o = make_float4(accum[nl][ch * 4 + 0] * rs,
                                   accum[nl][ch * 4 + 1] * rs,
                                   accum[nl][ch * 4 + 2] * rs,
                                   accum[nl][ch * 4 + 3] * rs);
            ve4[(size_t)n * 16 + ch] = o;
        }
    }
}

#define LDA 132  // padded row stride for A tile

// each thread computes 4 nodes x 4 dims
__device__ __forceinline__ void gemm4(float acc[4][4],
                                      const float* __restrict__ A,
                                      const float* __restrict__ Wb,
                                      int NG, int DG) {
    #pragma unroll 4
    for (int k = 0; k < 64; ++k) {
        const float4 w = *(const float4*)&Wb[k * 64 + DG];
        const float4 a = *(const float4*)&A[k * LDA + NG];
        const float av[4] = {a.x, a.y, a.z, a.w};
        const float wv[4] = {w.x, w.y, w.z, w.w};
        #pragma unroll
        for (int i = 0; i < 4; ++i)
            #pragma unroll
            for (int j = 0; j < 4; ++j)
                acc[i][j] = fmaf(av[i], wv[j], acc[i][j]);
    }
}

__global__ __launch_bounds__(512) void mlp_k(const float* __restrict__ x,
                                             const int* __restrict__ batch,
                                             const float* __restrict__ W1,
                                             const float* __restrict__ W2,
                                             const float* __restrict__ b2,
                                             const float* __restrict__ ve,
                                             const float* __restrict__ U1,
                                             float* __restrict__ out) {
    __shared__ float A[64 * LDA];
    __shared__ float Wb[64 * 64];

    const int t = threadIdx.x;        // 0..511
    const int c = t & 15;             // staging k-chunk
    const int rb = t >> 4;            // 0..31
    const int DG = (t & 15) * 4;      // 4 output dims
    const int NG = (t >> 4) * 4;      // 4 local nodes
    const int n0 = blockIdx.x * TM;

    float acc[4][4];

    #pragma unroll
    for (int i = 0; i < 4; ++i) {
        int n = n0 + NG + i;
        int b = (n < NN) ? batch[n] : 0;
        const float4 uv = *(const float4*)&U1[b * DIM + DG];
        acc[i][0] = uv.x; acc[i][1] = uv.y; acc[i][2] = uv.z; acc[i][3] = uv.w;
    }

    // ---------- pass 1: x @ W1[0:64] ----------
    #pragma unroll
    for (int it = 0; it < 4; ++it) {
        int r = rb + it * 32;
        int n = n0 + r;
        float4 v = make_float4(0.f, 0.f, 0.f, 0.f);
        if (n < NN) v = *(const float4*)&x[(size_t)n * DIM + c * 4];
        A[(c * 4 + 0) * LDA + r] = v.x;
        A[(c * 4 + 1) * LDA + r] = v.y;
        A[(c * 4 + 2) * LDA + r] = v.z;
        A[(c * 4 + 3) * LDA + r] = v.w;
    }
    #pragma unroll
    for (int it = 0; it < 2; ++it) {
        int r = rb + it * 32;
        *(float4*)&Wb[r * 64 + c * 4] = *(const float4*)&W1[(size_t)r * DIM + c * 4];
    }
    __syncthreads();
    gemm4(acc, A, Wb, NG, DG);
    __syncthreads();

    // ---------- pass 2: v_e @ W1[64:128] ----------
    #pragma unroll
    for (int it = 0; it < 4; ++it) {
        int r = rb + it * 32;
        int n = n0 + r;
        float4 v = make_float4(0.f, 0.f, 0.f, 0.f);
        if (n < NN) v = *(const float4*)&ve[(size_t)n * DIM + c * 4];
        A[(c * 4 + 0) * LDA + r] = v.x;
        A[(c * 4 + 1) * LDA + r] = v.y;
        A[(c * 4 + 2) * LDA + r] = v.z;
        A[(c * 4 + 3) * LDA + r] = v.w;
    }
    #pragma unroll
    for (int it = 0; it < 2; ++it) {
        int r = rb + it * 32;
        *(float4*)&Wb[r * 64 + c * 4] = *(const float4*)&W1[(size_t)(64 + r) * DIM + c * 4];
    }
    __syncthreads();
    gemm4(acc, A, Wb, NG, DG);

    #pragma unroll
    for (int i = 0; i < 4; ++i)
        #pragma unroll
        for (int j = 0; j < 4; ++j)
            acc[i][j] = fmaxf(acc[i][j], 0.f);

    __syncthreads();

    // ---------- layer 2: h @ W2 ----------
    #pragma unroll
    for (int j = 0; j < 4; ++j) {
        float4 h = make_float4(acc[0][j], acc[1][j], acc[2][j], acc[3][j]);
        *(float4*)&A[(DG + j) * LDA + NG] = h;
    }
    #pragma unroll
    for (int it = 0; it < 2; ++it) {
        int r = rb + it * 32;
        *(float4*)&Wb[r * 64 + c * 4] = *(const float4*)&W2[(size_t)r * DIM + c * 4];
    }
    __syncthreads();

    {
        const float4 bv = *(const float4*)&b2[DG];
        #pragma unroll
        for (int i = 0; i < 4; ++i) {
            acc[i][0] = bv.x; acc[i][1] = bv.y; acc[i][2] = bv.z; acc[i][3] = bv.w;
        }
    }
    gemm4(acc, A, Wb, NG, DG);

    #pragma unroll
    for (int i = 0; i < 4; ++i) {
        int n = n0 + NG + i;
        if (n < NN) {
            float4 o = make_float4(acc[i][0], acc[i][1], acc[i][2], acc[i][3]);
            *(float4*)&out[(size_t)n * DIM + DG] = o;
        }
    }
}

extern "C" void kernel_launch(void* const* d_in, const int* in_sizes, int n_in,
                              void* d_out, int out_size, void* d_ws, size_t ws_size,
                              hipStream_t stream)
{
    const float* x     = (const float*)d_in[0];
    const int*   eidx  = (const int*)d_in[1];    // [2,E], row 0 = src
    const float* ea    = (const float*)d_in[2];
    const float* u     = (const float*)d_in[3];
    const int*   batch = (const int*)d_in[4];
    const float* W1    = (const float*)d_in[5];
    const float* b1    = (const float*)d_in[6];
    const float* W2    = (const float*)d_in[7];
    const float* b2    = (const float*)d_in[8];
    float* out = (float*)d_out;

    float* ve     = (float*)d_ws;                      // NN*DIM floats
    float* U1     = ve + (size_t)NN * DIM;             // NB*DIM floats
    int*   bbuf   = (int*)(U1 + NB * DIM);             // NBLK_A*EB ints
    int*   blkoff = bbuf + (size_t)NBLK_A * EB;        // NBLK_A*(NBKT+1) ints

    bucketA_k<<<NBLK_A, 1024, 0, stream>>>(eidx, bbuf, blkoff, u, W1, b1, U1);
    aggB_k<<<NBKT, 1024, 0, stream>>>(eidx, bbuf, blkoff, (const vfloat4*)ea, (float4*)ve);
    mlp_k<<<(NN + TM - 1) / TM, 512, 0, stream>>>(x, batch, W1, W2, b2, ve, U1, out);
}

// Round 15
// 98.888 us; speedup vs baseline: 4.1814x; 4.1814x over previous
//
#include <hip/hip_runtime.h>

#define NN 50000
#define NE 800000
#define NB 64
#define DIM 64
#define TM 128
#define CAP 64        // per-node CSR capacity; max deg ~40
#define EB 4096       // edges per bucketA block
#define NBLK_A 196    // ceil(NE/EB)
#define NBKT 196      // buckets of 256 nodes

typedef float vfloat4 __attribute__((ext_vector_type(4)));

// ws: deg[NN] | eids[NN*CAP] | U1[NB*DIM f32] | ve[NN*DIM f32] | bbuf[NBLK_A*EB] | blkoff[NBLK_A*(NBKT+1)]

// Pass A: per-block LDS counting-sort of 4096 edges by bucket (s>>8).
__global__ __launch_bounds__(1024) void bucketA_k(const int* __restrict__ src,
                                                  int* __restrict__ bbuf,
                                                  int* __restrict__ blkoff,
                                                  const float* __restrict__ u,
                                                  const float* __restrict__ W1,
                                                  const float* __restrict__ b1,
                                                  float* __restrict__ U1) {
    __shared__ int hist[NBKT];
    __shared__ int cnt2[NBKT];
    __shared__ int off[NBKT + 1];
    __shared__ int sortedE[EB];

    const int tid = threadIdx.x;
    const int blk = blockIdx.x;

    for (int i = tid; i < NBKT; i += 1024) { hist[i] = 0; cnt2[i] = 0; }
    __syncthreads();

    const int e0 = (blk * 1024 + tid) * 4;
    const bool valid = (e0 < NE);
    int4 s4 = make_int4(0, 0, 0, 0);
    if (valid) s4 = ((const int4*)src)[e0 >> 2];
    const int bk0 = s4.x >> 8, bk1 = s4.y >> 8, bk2 = s4.z >> 8, bk3 = s4.w >> 8;

    if (valid) {
        atomicAdd(&hist[bk0], 1);
        atomicAdd(&hist[bk1], 1);
        atomicAdd(&hist[bk2], 1);
        atomicAdd(&hist[bk3], 1);
    }
    __syncthreads();

    if (tid < 64) {
        const int base = tid * 4;
        int a0 = 0, a1 = 0, a2 = 0, a3 = 0;
        if (base < NBKT) {
            a0 = hist[base + 0]; a1 = hist[base + 1];
            a2 = hist[base + 2]; a3 = hist[base + 3];
        }
        const int sum = a0 + a1 + a2 + a3;
        int run = sum;
        #pragma unroll
        for (int m = 1; m < 64; m <<= 1) {
            int v = __shfl_up(run, m, 64);
            if (tid >= m) run += v;
        }
        const int excl = run - sum;
        if (base < NBKT) {
            off[base + 0] = excl;
            off[base + 1] = excl + a0;
            off[base + 2] = excl + a0 + a1;
            off[base + 3] = excl + a0 + a1 + a2;
        }
        if (tid == 63) off[NBKT] = run;
    }
    __syncthreads();

    if (valid) {
        int r0 = off[bk0] + atomicAdd(&cnt2[bk0], 1); sortedE[r0] = e0 + 0;
        int r1 = off[bk1] + atomicAdd(&cnt2[bk1], 1); sortedE[r1] = e0 + 1;
        int r2 = off[bk2] + atomicAdd(&cnt2[bk2], 1); sortedE[r2] = e0 + 2;
        int r3 = off[bk3] + atomicAdd(&cnt2[bk3], 1); sortedE[r3] = e0 + 3;
    }
    __syncthreads();

    const int nE = min(EB, NE - blk * EB);
    for (int i = tid; i < nE; i += 1024)
        bbuf[blk * EB + i] = sortedE[i];
    for (int i = tid; i <= NBKT; i += 1024)
        blkoff[blk * (NBKT + 1) + i] = off[i];

    if (blk < NB && tid < DIM) {
        float a = b1[tid];
        const float* up = u + blk * DIM;
        #pragma unroll 8
        for (int k = 0; k < DIM; ++k)
            a = fmaf(up[k], W1[(2 * DIM + k) * DIM + tid], a);
        U1[blk * DIM + tid] = a;
    }
}

// Pass B: one block per bucket; LDS-atomic rank over 256 node counters; write eids+deg.
__global__ __launch_bounds__(1024) void placeB_k(const int* __restrict__ src,
                                                 const int* __restrict__ bbuf,
                                                 const int* __restrict__ blkoff,
                                                 int* __restrict__ eids,
                                                 int* __restrict__ deg) {
    __shared__ int cnt[256];
    __shared__ int lo_s[NBLK_A], hi_s[NBLK_A];
    __shared__ int segoff[NBLK_A + 1];

    const int b = blockIdx.x;
    const int tid = threadIdx.x;

    if (tid < 256) cnt[tid] = 0;
    if (tid < NBLK_A) {
        lo_s[tid] = blkoff[tid * (NBKT + 1) + b];
        hi_s[tid] = blkoff[tid * (NBKT + 1) + b + 1];
    }
    __syncthreads();

    if (tid < 64) {
        const int base = tid * 4;
        int a0 = 0, a1 = 0, a2 = 0, a3 = 0;
        if (base < NBLK_A) {
            a0 = hi_s[base + 0] - lo_s[base + 0];
            a1 = hi_s[base + 1] - lo_s[base + 1];
            a2 = hi_s[base + 2] - lo_s[base + 2];
            a3 = hi_s[base + 3] - lo_s[base + 3];
        }
        const int sum = a0 + a1 + a2 + a3;
        int run = sum;
        #pragma unroll
        for (int m = 1; m < 64; m <<= 1) {
            int v = __shfl_up(run, m, 64);
            if (tid >= m) run += v;
        }
        const int excl = run - sum;
        if (base < NBLK_A) {
            segoff[base + 0] = excl;
            segoff[base + 1] = excl + a0;
            segoff[base + 2] = excl + a0 + a1;
            segoff[base + 3] = excl + a0 + a1 + a2;
        }
        if (tid == 63) segoff[NBLK_A] = run;
    }
    __syncthreads();

    const int total = segoff[NBLK_A];
    for (int i = tid; i < total; i += 1024) {
        int lo2 = 0, hi2 = NBLK_A;
        while (lo2 + 1 < hi2) {
            int mid = (lo2 + hi2) >> 1;
            if (segoff[mid] <= i) lo2 = mid; else hi2 = mid;
        }
        const int blk = lo2;
        const int idx = i - segoff[blk] + lo_s[blk];
        const int e = bbuf[blk * EB + idx];
        const int s = src[e];
        const int rank = atomicAdd(&cnt[s & 255], 1);
        eids[s * CAP + rank] = e;
    }
    __syncthreads();

    const int s = b * 256 + tid;
    if (tid < 256 && s < NN) deg[s] = cnt[tid];
}

// one wave per node; 4 edge slots x 16 float4 chunks; unconditional clamped gathers.
__global__ __launch_bounds__(256) void reduce_k(const int* __restrict__ deg_arr,
                                                const int* __restrict__ eids,
                                                const vfloat4* __restrict__ ea4,
                                                float4* __restrict__ ve4) {
    int n = (blockIdx.x * 256 + threadIdx.x) >> 6;   // grid exactly NN*64 threads
    int lane = threadIdx.x & 63;
    int chunk = lane & 15, slot = lane >> 4;
    int deg = deg_arr[n];
    const int* ebase = eids + (size_t)n * CAP;

    vfloat4 acc = {0.f, 0.f, 0.f, 0.f};
    const vfloat4 vzero = {0.f, 0.f, 0.f, 0.f};

    if (deg > 0) {
        int dm1 = deg - 1;
        int e[8];
        #pragma unroll
        for (int r = 0; r < 8; ++r) {
            int j = slot + r * 4;
            e[r] = ebase[j < dm1 ? j : dm1];
        }
        #pragma unroll
        for (int r = 0; r < 8; ++r) {
            vfloat4 v = __builtin_nontemporal_load(&ea4[(size_t)e[r] * 16 + chunk]);
            acc += (slot + r * 4 < deg) ? v : vzero;
        }
        for (int j = 32 + slot; j < deg; j += 4) {   // rare tail: 32 < deg <= CAP
            int ee = ebase[j];
            vfloat4 v = __builtin_nontemporal_load(&ea4[(size_t)ee * 16 + chunk]);
            acc += v;
        }
    }

    #pragma unroll
    for (int m = 16; m <= 32; m <<= 1) {
        acc.x += __shfl_xor(acc.x, m, 64);
        acc.y += __shfl_xor(acc.y, m, 64);
        acc.z += __shfl_xor(acc.z, m, 64);
        acc.w += __shfl_xor(acc.w, m, 64);
    }
    if (slot == 0) {
        float rs = 1.0f / fmaxf((float)deg, 1.0f);
        ve4[(size_t)n * 16 + chunk] = make_float4(acc.x * rs, acc.y * rs, acc.z * rs, acc.w * rs);
    }
}

#define LDA 132  // padded row stride for A tile

// 256 threads; each computes 8 nodes x 4 dims; 1.5 DS-bytes/FMA read path
__device__ __forceinline__ void gemm8(float acc[8][4],
                                      const float* __restrict__ A,
                                      const float* __restrict__ Wb,
                                      int NG, int DG) {
    #pragma unroll 4
    for (int k = 0; k < 64; ++k) {
        const float4 w  = *(const float4*)&Wb[k * 64 + DG];
        const float4 a0 = *(const float4*)&A[k * LDA + NG];
        const float4 a1 = *(const float4*)&A[k * LDA + NG + 4];
        const float av[8] = {a0.x, a0.y, a0.z, a0.w, a1.x, a1.y, a1.z, a1.w};
        const float wv[4] = {w.x, w.y, w.z, w.w};
        #pragma unroll
        for (int i = 0; i < 8; ++i)
            #pragma unroll
            for (int j = 0; j < 4; ++j)
                acc[i][j] = fmaf(av[i], wv[j], acc[i][j]);
    }
}

// register-transpose staging: thread loads 4 node-rows (float4 each) of its
// dim-group, transposes 4x4 in regs, writes 4 ds_write_b128 (vs 16 ds_write_b32).
__device__ __forceinline__ void stage_T(float* __restrict__ A,
                                        const float* __restrict__ srcm,
                                        int n0, int c, int rb) {
    #pragma unroll
    for (int it = 0; it < 2; ++it) {
        const int g = rb + it * 16;           // node group 0..31
        float4 v[4];
        #pragma unroll
        for (int i = 0; i < 4; ++i) {
            const int n = n0 + g * 4 + i;
            v[i] = make_float4(0.f, 0.f, 0.f, 0.f);
            if (n < NN) v[i] = *(const float4*)&srcm[(size_t)n * DIM + c * 4];
        }
        #pragma unroll
        for (int j = 0; j < 4; ++j) {
            float4 row;
            row.x = (&v[0].x)[j]; row.y = (&v[1].x)[j];
            row.z = (&v[2].x)[j]; row.w = (&v[3].x)[j];
            *(float4*)&A[(c * 4 + j) * LDA + g * 4] = row;
        }
    }
}

__global__ __launch_bounds__(256) void mlp_k(const float* __restrict__ x,
                                             const int* __restrict__ batch,
                                             const float* __restrict__ W1,
                                             const float* __restrict__ W2,
                                             const float* __restrict__ b2,
                                             const float* __restrict__ ve,
                                             const float* __restrict__ U1,
                                             float* __restrict__ out) {
    __shared__ float A[64 * LDA];
    __shared__ float Wb[64 * 64];

    const int t = threadIdx.x;        // 0..255
    const int c = t & 15;
    const int rb = t >> 4;            // 0..15
    const int DG = c * 4;
    const int NG = rb * 8;
    const int n0 = blockIdx.x * TM;

    float acc[8][4];

    #pragma unroll
    for (int i = 0; i < 8; ++i) {
        int n = n0 + NG + i;
        int b = (n < NN) ? batch[n] : 0;
        const float4 uv = *(const float4*)&U1[b * DIM + DG];
        acc[i][0] = uv.x; acc[i][1] = uv.y; acc[i][2] = uv.z; acc[i][3] = uv.w;
    }

    // ---------- pass 1: x @ W1[0:64] ----------
    stage_T(A, x, n0, c, rb);
    #pragma unroll
    for (int it = 0; it < 4; ++it) {
        int r = rb + it * 16;
        *(float4*)&Wb[r * 64 + c * 4] = *(const float4*)&W1[(size_t)r * DIM + c * 4];
    }
    __syncthreads();
    gemm8(acc, A, Wb, NG, DG);
    __syncthreads();

    // ---------- pass 2: v_e @ W1[64:128] ----------
    stage_T(A, ve, n0, c, rb);
    #pragma unroll
    for (int it = 0; it < 4; ++it) {
        int r = rb + it * 16;
        *(float4*)&Wb[r * 64 + c * 4] = *(const float4*)&W1[(size_t)(64 + r) * DIM + c * 4];
    }
    __syncthreads();
    gemm8(acc, A, Wb, NG, DG);

    #pragma unroll
    for (int i = 0; i < 8; ++i)
        #pragma unroll
        for (int j = 0; j < 4; ++j)
            acc[i][j] = fmaxf(acc[i][j], 0.f);

    __syncthreads();

    // ---------- layer 2: h @ W2 ----------
    #pragma unroll
    for (int j = 0; j < 4; ++j) {
        float4 h0 = make_float4(acc[0][j], acc[1][j], acc[2][j], acc[3][j]);
        float4 h1 = make_float4(acc[4][j], acc[5][j], acc[6][j], acc[7][j]);
        *(float4*)&A[(DG + j) * LDA + NG]     = h0;
        *(float4*)&A[(DG + j) * LDA + NG + 4] = h1;
    }
    #pragma unroll
    for (int it = 0; it < 4; ++it) {
        int r = rb + it * 16;
        *(float4*)&Wb[r * 64 + c * 4] = *(const float4*)&W2[(size_t)r * DIM + c * 4];
    }
    __syncthreads();

    {
        const float4 bv = *(const float4*)&b2[DG];
        #pragma unroll
        for (int i = 0; i < 8; ++i) {
            acc[i][0] = bv.x; acc[i][1] = bv.y; acc[i][2] = bv.z; acc[i][3] = bv.w;
        }
    }
    gemm8(acc, A, Wb, NG, DG);

    #pragma unroll
    for (int i = 0; i < 8; ++i) {
        int n = n0 + NG + i;
        if (n < NN) {
            float4 o = make_float4(acc[i][0], acc[i][1], acc[i][2], acc[i][3]);
            *(float4*)&out[(size_t)n * DIM + DG] = o;
        }
    }
}

extern "C" void kernel_launch(void* const* d_in, const int* in_sizes, int n_in,
                              void* d_out, int out_size, void* d_ws, size_t ws_size,
                              hipStream_t stream)
{
    const float* x     = (const float*)d_in[0];
    const int*   eidx  = (const int*)d_in[1];    // [2,E], row 0 = src
    const float* ea    = (const float*)d_in[2];
    const float* u     = (const float*)d_in[3];
    const int*   batch = (const int*)d_in[4];
    const float* W1    = (const float*)d_in[5];
    const float* b1    = (const float*)d_in[6];
    const float* W2    = (const float*)d_in[7];
    const float* b2    = (const float*)d_in[8];
    float* out = (float*)d_out;

    int*   deg    = (int*)d_ws;                        // NN ints
    int*   eids   = deg + NN;                          // NN*CAP ints
    float* U1     = (float*)(eids + (size_t)NN * CAP); // NB*DIM floats
    float* ve     = U1 + NB * DIM;                     // NN*DIM floats
    int*   bbuf   = (int*)(ve + (size_t)NN * DIM);     // NBLK_A*EB ints
    int*   blkoff = bbuf + (size_t)NBLK_A * EB;        // NBLK_A*(NBKT+1) ints

    bucketA_k<<<NBLK_A, 1024, 0, stream>>>(eidx, bbuf, blkoff, u, W1, b1, U1);
    placeB_k<<<NBKT, 1024, 0, stream>>>(eidx, bbuf, blkoff, eids, deg);
    reduce_k<<<(NN * 64) / 256, 256, 0, stream>>>(deg, eids, (const vfloat4*)ea, (float4*)ve);
    mlp_k<<<(NN + TM - 1) / TM, 256, 0, stream>>>(x, batch, W1, W2, b2, ve, U1, out);
}

// Round 16
// 89.470 us; speedup vs baseline: 4.6215x; 1.1053x over previous
//
#include <hip/hip_runtime.h>

#define NN 50000
#define NE 800000
#define NB 64
#define DIM 64
#define TM 128
#define CAP 64        // per-node rank capacity in LDS; max deg ~40
#define EB 4096       // edges per bucketA block
#define NBLK_A 196    // ceil(NE/EB)
#define NBKT 392      // buckets of 128 nodes (s>>7); block 391 is empty-guarded
#define BN 128        // nodes per bucket

typedef float vfloat4 __attribute__((ext_vector_type(4)));

// ws: ve[NN*DIM f32] | U1[NB*DIM f32] | bbuf[NBLK_A*EB] | blkoff[NBLK_A*(NBKT+1)]
// eids/deg never touch HBM.

// Pass A: per-block LDS counting-sort of 4096 edges by bucket (s>>7).
// Coalesced writes; NO global atomics. blocks 0..63 also premix U1.
__global__ __launch_bounds__(1024) void bucketA_k(const int* __restrict__ src,
                                                  int* __restrict__ bbuf,
                                                  int* __restrict__ blkoff,
                                                  const float* __restrict__ u,
                                                  const float* __restrict__ W1,
                                                  const float* __restrict__ b1,
                                                  float* __restrict__ U1) {
    __shared__ int hist[NBKT];
    __shared__ int cnt2[NBKT];
    __shared__ int off[NBKT + 1];
    __shared__ int sortedE[EB];

    const int tid = threadIdx.x;
    const int blk = blockIdx.x;

    for (int i = tid; i < NBKT; i += 1024) { hist[i] = 0; cnt2[i] = 0; }
    __syncthreads();

    const int e0 = (blk * 1024 + tid) * 4;
    const bool valid = (e0 < NE);
    int4 s4 = make_int4(0, 0, 0, 0);
    if (valid) s4 = ((const int4*)src)[e0 >> 2];
    const int bk0 = s4.x >> 7, bk1 = s4.y >> 7, bk2 = s4.z >> 7, bk3 = s4.w >> 7;

    if (valid) {
        atomicAdd(&hist[bk0], 1);
        atomicAdd(&hist[bk1], 1);
        atomicAdd(&hist[bk2], 1);
        atomicAdd(&hist[bk3], 1);
    }
    __syncthreads();

    // exclusive scan of hist[392] by wave 0: 8 buckets per lane
    if (tid < 64) {
        const int base = tid * 8;
        int a[8];
        int sum = 0;
        #pragma unroll
        for (int i = 0; i < 8; ++i) {
            a[i] = (base + i < NBKT) ? hist[base + i] : 0;
            sum += a[i];
        }
        int run = sum;
        #pragma unroll
        for (int m = 1; m < 64; m <<= 1) {
            int v = __shfl_up(run, m, 64);
            if (tid >= m) run += v;
        }
        int acc2 = run - sum;
        #pragma unroll
        for (int i = 0; i < 8; ++i) {
            if (base + i < NBKT) off[base + i] = acc2;
            acc2 += a[i];
        }
        if (tid == 63) off[NBKT] = run;   // block's edge count
    }
    __syncthreads();

    if (valid) {
        int r0 = off[bk0] + atomicAdd(&cnt2[bk0], 1); sortedE[r0] = e0 + 0;
        int r1 = off[bk1] + atomicAdd(&cnt2[bk1], 1); sortedE[r1] = e0 + 1;
        int r2 = off[bk2] + atomicAdd(&cnt2[bk2], 1); sortedE[r2] = e0 + 2;
        int r3 = off[bk3] + atomicAdd(&cnt2[bk3], 1); sortedE[r3] = e0 + 3;
    }
    __syncthreads();

    const int nE = min(EB, NE - blk * EB);
    for (int i = tid; i < nE; i += 1024)
        bbuf[blk * EB + i] = sortedE[i];
    for (int i = tid; i <= NBKT; i += 1024)
        blkoff[blk * (NBKT + 1) + i] = off[i];

    if (blk < NB && tid < DIM) {
        float a = b1[tid];
        const float* up = u + blk * DIM;
        #pragma unroll 8
        for (int k = 0; k < DIM; ++k)
            a = fmaf(up[k], W1[(2 * DIM + k) * DIM + tid], a);
        U1[blk * DIM + tid] = a;
    }
}

// Fused place+reduce: one block per 128-node bucket.
// Phase 1 (= round-12 placeB, LDS-resident eids): binsearch -> bbuf -> src
//   -> LDS int rank -> eids_l (LDS).
// Phase 2 (= reduce_k shape): wave w sweeps 8 nodes; 8 clamped 256B ea rows
//   in flight; shfl-reduce; coalesced ve write. 64KB/CU outstanding, same as reduce_k.
__global__ __launch_bounds__(1024) void placeRed_k(const int* __restrict__ src,
                                                   const int* __restrict__ bbuf,
                                                   const int* __restrict__ blkoff,
                                                   const vfloat4* __restrict__ ea4,
                                                   float4* __restrict__ ve4) {
    __shared__ int eids_l[BN * CAP];    // 32 KB
    __shared__ int cnt[BN];
    __shared__ int lo_s[NBLK_A], hi_s[NBLK_A];
    __shared__ int segoff[NBLK_A + 1];

    const int b = blockIdx.x;
    const int tid = threadIdx.x;

    if (tid < BN) cnt[tid] = 0;
    if (tid < NBLK_A) {
        lo_s[tid] = blkoff[tid * (NBKT + 1) + b];
        hi_s[tid] = blkoff[tid * (NBKT + 1) + b + 1];
    }
    __syncthreads();

    // exclusive scan of 196 segment lengths by wave 0 (4 per lane)
    if (tid < 64) {
        const int base = tid * 4;
        int a0 = 0, a1 = 0, a2 = 0, a3 = 0;
        if (base < NBLK_A) {
            a0 = hi_s[base + 0] - lo_s[base + 0];
            a1 = hi_s[base + 1] - lo_s[base + 1];
            a2 = hi_s[base + 2] - lo_s[base + 2];
            a3 = hi_s[base + 3] - lo_s[base + 3];
        }
        const int sum = a0 + a1 + a2 + a3;
        int run = sum;
        #pragma unroll
        for (int m = 1; m < 64; m <<= 1) {
            int v = __shfl_up(run, m, 64);
            if (tid >= m) run += v;
        }
        const int excl = run - sum;
        if (base < NBLK_A) {
            segoff[base + 0] = excl;
            segoff[base + 1] = excl + a0;
            segoff[base + 2] = excl + a0 + a1;
            segoff[base + 3] = excl + a0 + a1 + a2;
        }
        if (tid == 63) segoff[NBLK_A] = run;
    }
    __syncthreads();

    // ---- phase 1: rank + place into LDS ----
    const int total = segoff[NBLK_A];
    for (int i = tid; i < total; i += 1024) {
        int lo2 = 0, hi2 = NBLK_A;
        while (lo2 + 1 < hi2) {
            int mid = (lo2 + hi2) >> 1;
            if (segoff[mid] <= i) lo2 = mid; else hi2 = mid;
        }
        const int blk = lo2;
        const int idx = i - segoff[blk] + lo_s[blk];
        const int e = bbuf[blk * EB + idx];
        const int s = src[e];
        const int nl = s & (BN - 1);
        const int rank = atomicAdd(&cnt[nl], 1);
        if (rank < CAP) eids_l[nl * CAP + rank] = e;
    }
    __syncthreads();

    // ---- phase 2: gather-reduce (reduce_k shape) ----
    const int wave = tid >> 6, lane = tid & 63;
    const int chunk = lane & 15, slot = lane >> 4;
    const vfloat4 vzero = {0.f, 0.f, 0.f, 0.f};

    #pragma unroll
    for (int m = 0; m < BN / 16; ++m) {          // 8 nodes per wave
        const int nl = wave * (BN / 16) + m;
        const int n = b * BN + nl;
        if (n >= NN) break;
        const int deg = min(cnt[nl], CAP);
        const int* ebase = eids_l + nl * CAP;

        vfloat4 acc = vzero;
        if (deg > 0) {
            const int dm1 = deg - 1;
            int e[8];
            #pragma unroll
            for (int r = 0; r < 8; ++r) {
                int j = slot + r * 4;
                e[r] = ebase[j < dm1 ? j : dm1];
            }
            #pragma unroll
            for (int r = 0; r < 8; ++r) {
                vfloat4 v = __builtin_nontemporal_load(&ea4[(size_t)e[r] * 16 + chunk]);
                acc += (slot + r * 4 < deg) ? v : vzero;
            }
            for (int j = 32 + slot; j < deg; j += 4) {   // rare tail: 32 < deg <= CAP
                int ee = ebase[j];
                vfloat4 v = __builtin_nontemporal_load(&ea4[(size_t)ee * 16 + chunk]);
                acc += v;
            }
        }
        #pragma unroll
        for (int mm = 16; mm <= 32; mm <<= 1) {
            acc.x += __shfl_xor(acc.x, mm, 64);
            acc.y += __shfl_xor(acc.y, mm, 64);
            acc.z += __shfl_xor(acc.z, mm, 64);
            acc.w += __shfl_xor(acc.w, mm, 64);
        }
        if (slot == 0) {
            const float rs = 1.0f / fmaxf((float)cnt[nl], 1.0f);
            ve4[(size_t)n * 16 + chunk] =
                make_float4(acc.x * rs, acc.y * rs, acc.z * rs, acc.w * rs);
        }
    }
}

#define LDA 132  // padded row stride for A tile

// round-12 mlp: 512 threads, each computes 4 nodes x 4 dims
__device__ __forceinline__ void gemm4(float acc[4][4],
                                      const float* __restrict__ A,
                                      const float* __restrict__ Wb,
                                      int NG, int DG) {
    #pragma unroll 4
    for (int k = 0; k < 64; ++k) {
        const float4 w = *(const float4*)&Wb[k * 64 + DG];
        const float4 a = *(const float4*)&A[k * LDA + NG];
        const float av[4] = {a.x, a.y, a.z, a.w};
        const float wv[4] = {w.x, w.y, w.z, w.w};
        #pragma unroll
        for (int i = 0; i < 4; ++i)
            #pragma unroll
            for (int j = 0; j < 4; ++j)
                acc[i][j] = fmaf(av[i], wv[j], acc[i][j]);
    }
}

__global__ __launch_bounds__(512) void mlp_k(const float* __restrict__ x,
                                             const int* __restrict__ batch,
                                             const float* __restrict__ W1,
                                             const float* __restrict__ W2,
                                             const float* __restrict__ b2,
                                             const float* __restrict__ ve,
                                             const float* __restrict__ U1,
                                             float* __restrict__ out) {
    __shared__ float A[64 * LDA];
    __shared__ float Wb[64 * 64];

    const int t = threadIdx.x;        // 0..511
    const int c = t & 15;
    const int rb = t >> 4;            // 0..31
    const int DG = (t & 15) * 4;
    const int NG = (t >> 4) * 4;
    const int n0 = blockIdx.x * TM;

    float acc[4][4];

    #pragma unroll
    for (int i = 0; i < 4; ++i) {
        int n = n0 + NG + i;
        int b = (n < NN) ? batch[n] : 0;
        const float4 uv = *(const float4*)&U1[b * DIM + DG];
        acc[i][0] = uv.x; acc[i][1] = uv.y; acc[i][2] = uv.z; acc[i][3] = uv.w;
    }

    // ---------- pass 1: x @ W1[0:64] ----------
    #pragma unroll
    for (int it = 0; it < 4; ++it) {
        int r = rb + it * 32;
        int n = n0 + r;
        float4 v = make_float4(0.f, 0.f, 0.f, 0.f);
        if (n < NN) v = *(const float4*)&x[(size_t)n * DIM + c * 4];
        A[(c * 4 + 0) * LDA + r] = v.x;
        A[(c * 4 + 1) * LDA + r] = v.y;
        A[(c * 4 + 2) * LDA + r] = v.z;
        A[(c * 4 + 3) * LDA + r] = v.w;
    }
    #pragma unroll
    for (int it = 0; it < 2; ++it) {
        int r = rb + it * 32;
        *(float4*)&Wb[r * 64 + c * 4] = *(const float4*)&W1[(size_t)r * DIM + c * 4];
    }
    __syncthreads();
    gemm4(acc, A, Wb, NG, DG);
    __syncthreads();

    // ---------- pass 2: v_e @ W1[64:128] ----------
    #pragma unroll
    for (int it = 0; it < 4; ++it) {
        int r = rb + it * 32;
        int n = n0 + r;
        float4 v = make_float4(0.f, 0.f, 0.f, 0.f);
        if (n < NN) v = *(const float4*)&ve[(size_t)n * DIM + c * 4];
        A[(c * 4 + 0) * LDA + r] = v.x;
        A[(c * 4 + 1) * LDA + r] = v.y;
        A[(c * 4 + 2) * LDA + r] = v.z;
        A[(c * 4 + 3) * LDA + r] = v.w;
    }
    #pragma unroll
    for (int it = 0; it < 2; ++it) {
        int r = rb + it * 32;
        *(float4*)&Wb[r * 64 + c * 4] = *(const float4*)&W1[(size_t)(64 + r) * DIM + c * 4];
    }
    __syncthreads();
    gemm4(acc, A, Wb, NG, DG);

    #pragma unroll
    for (int i = 0; i < 4; ++i)
        #pragma unroll
        for (int j = 0; j < 4; ++j)
            acc[i][j] = fmaxf(acc[i][j], 0.f);

    __syncthreads();

    // ---------- layer 2: h @ W2 ----------
    #pragma unroll
    for (int j = 0; j < 4; ++j) {
        float4 h = make_float4(acc[0][j], acc[1][j], acc[2][j], acc[3][j]);
        *(float4*)&A[(DG + j) * LDA + NG] = h;
    }
    #pragma unroll
    for (int it = 0; it < 2; ++it) {
        int r = rb + it * 32;
        *(float4*)&Wb[r * 64 + c * 4] = *(const float4*)&W2[(size_t)r * DIM + c * 4];
    }
    __syncthreads();

    {
        const float4 bv = *(const float4*)&b2[DG];
        #pragma unroll
        for (int i = 0; i < 4; ++i) {
            acc[i][0] = bv.x; acc[i][1] = bv.y; acc[i][2] = bv.z; acc[i][3] = bv.w;
        }
    }
    gemm4(acc, A, Wb, NG, DG);

    #pragma unroll
    for (int i = 0; i < 4; ++i) {
        int n = n0 + NG + i;
        if (n < NN) {
            float4 o = make_float4(acc[i][0], acc[i][1], acc[i][2], acc[i][3]);
            *(float4*)&out[(size_t)n * DIM + DG] = o;
        }
    }
}

extern "C" void kernel_launch(void* const* d_in, const int* in_sizes, int n_in,
                              void* d_out, int out_size, void* d_ws, size_t ws_size,
                              hipStream_t stream)
{
    const float* x     = (const float*)d_in[0];
    const int*   eidx  = (const int*)d_in[1];    // [2,E], row 0 = src
    const float* ea    = (const float*)d_in[2];
    const float* u     = (const float*)d_in[3];
    const int*   batch = (const int*)d_in[4];
    const float* W1    = (const float*)d_in[5];
    const float* b1    = (const float*)d_in[6];
    const float* W2    = (const float*)d_in[7];
    const float* b2    = (const float*)d_in[8];
    float* out = (float*)d_out;

    float* ve     = (float*)d_ws;                      // NN*DIM floats
    float* U1     = ve + (size_t)NN * DIM;             // NB*DIM floats
    int*   bbuf   = (int*)(U1 + NB * DIM);             // NBLK_A*EB ints
    int*   blkoff = bbuf + (size_t)NBLK_A * EB;        // NBLK_A*(NBKT+1) ints

    bucketA_k<<<NBLK_A, 1024, 0, stream>>>(eidx, bbuf, blkoff, u, W1, b1, U1);
    placeRed_k<<<NBKT, 1024, 0, stream>>>(eidx, bbuf, blkoff, (const vfloat4*)ea, (float4*)ve);
    mlp_k<<<(NN + TM - 1) / TM, 512, 0, stream>>>(x, batch, W1, W2, b2, ve, U1, out);
}

// Round 17
// 76.288 us; speedup vs baseline: 5.4201x; 1.1728x over previous
//
#include <hip/hip_runtime.h>

#define NN 50000
#define NE 800000
#define NB 64
#define DIM 64
#define CAP 64        // per-node rank capacity in LDS; max deg ~40
#define EB 4096       // edges per bucketA block
#define NBLK_A 196    // ceil(NE/EB)
#define NBKT 392      // buckets of 128 nodes (s>>7)
#define BN 128        // nodes per bucket
#define LDA 132       // padded A-tile row stride

typedef float vfloat4 __attribute__((ext_vector_type(4)));

// ws: U1[NB*DIM f32] | bbuf[NBLK_A*EB] | blkoff[NBLK_A*(NBKT+1)]
// bbuf entry packs edge id (bits 0..19) and node-in-bucket nl=s&127 (bits 20..26).

__global__ __launch_bounds__(1024) void bucketA_k(const int* __restrict__ src,
                                                  int* __restrict__ bbuf,
                                                  int* __restrict__ blkoff,
                                                  const float* __restrict__ u,
                                                  const float* __restrict__ W1,
                                                  const float* __restrict__ b1,
                                                  float* __restrict__ U1) {
    __shared__ int hist[NBKT];
    __shared__ int cnt2[NBKT];
    __shared__ int off[NBKT + 1];
    __shared__ int sortedE[EB];

    const int tid = threadIdx.x;
    const int blk = blockIdx.x;

    for (int i = tid; i < NBKT; i += 1024) { hist[i] = 0; cnt2[i] = 0; }
    __syncthreads();

    const int e0 = (blk * 1024 + tid) * 4;
    const bool valid = (e0 < NE);
    int4 s4 = make_int4(0, 0, 0, 0);
    if (valid) s4 = ((const int4*)src)[e0 >> 2];
    const int bk0 = s4.x >> 7, bk1 = s4.y >> 7, bk2 = s4.z >> 7, bk3 = s4.w >> 7;

    if (valid) {
        atomicAdd(&hist[bk0], 1);
        atomicAdd(&hist[bk1], 1);
        atomicAdd(&hist[bk2], 1);
        atomicAdd(&hist[bk3], 1);
    }
    __syncthreads();

    // exclusive scan of hist[392] by wave 0: 8 buckets per lane
    if (tid < 64) {
        const int base = tid * 8;
        int a[8];
        int sum = 0;
        #pragma unroll
        for (int i = 0; i < 8; ++i) {
            a[i] = (base + i < NBKT) ? hist[base + i] : 0;
            sum += a[i];
        }
        int run = sum;
        #pragma unroll
        for (int m = 1; m < 64; m <<= 1) {
            int v = __shfl_up(run, m, 64);
            if (tid >= m) run += v;
        }
        int acc2 = run - sum;
        #pragma unroll
        for (int i = 0; i < 8; ++i) {
            if (base + i < NBKT) off[base + i] = acc2;
            acc2 += a[i];
        }
        if (tid == 63) off[NBKT] = run;
    }
    __syncthreads();

    if (valid) {
        int r0 = off[bk0] + atomicAdd(&cnt2[bk0], 1); sortedE[r0] = (e0 + 0) | ((s4.x & 127) << 20);
        int r1 = off[bk1] + atomicAdd(&cnt2[bk1], 1); sortedE[r1] = (e0 + 1) | ((s4.y & 127) << 20);
        int r2 = off[bk2] + atomicAdd(&cnt2[bk2], 1); sortedE[r2] = (e0 + 2) | ((s4.z & 127) << 20);
        int r3 = off[bk3] + atomicAdd(&cnt2[bk3], 1); sortedE[r3] = (e0 + 3) | ((s4.w & 127) << 20);
    }
    __syncthreads();

    const int nE = min(EB, NE - blk * EB);
    for (int i = tid; i < nE; i += 1024)
        bbuf[blk * EB + i] = sortedE[i];
    for (int i = tid; i <= NBKT; i += 1024)
        blkoff[blk * (NBKT + 1) + i] = off[i];

    if (blk < NB && tid < DIM) {
        float a = b1[tid];
        const float* up = u + blk * DIM;
        #pragma unroll 8
        for (int k = 0; k < DIM; ++k)
            a = fmaf(up[k], W1[(2 * DIM + k) * DIM + tid], a);
        U1[blk * DIM + tid] = a;
    }
}

// 512 threads, each computes 4 nodes x 4 dims (r12-proven shape)
__device__ __forceinline__ void gemm4(float acc[4][4],
                                      const float* __restrict__ A,
                                      const float* __restrict__ Wb,
                                      int NG, int DG) {
    #pragma unroll 4
    for (int k = 0; k < 64; ++k) {
        const float4 w = *(const float4*)&Wb[k * 64 + DG];
        const float4 a = *(const float4*)&A[k * LDA + NG];
        const float av[4] = {a.x, a.y, a.z, a.w};
        const float wv[4] = {w.x, w.y, w.z, w.w};
        #pragma unroll
        for (int i = 0; i < 4; ++i)
            #pragma unroll
            for (int j = 0; j < 4; ++j)
                acc[i][j] = fmaf(av[i], wv[j], acc[i][j]);
    }
}

// Fused place+reduce+MLP: one 512-thread block per 128-node bucket.
// Phase 1: rank packed edges into LDS eids_l (LDS int atomics only).
// Phase 2: r16 gather shape (8 waves x 16 nodes, 8 clamped 256B rows in
//          flight), v_e written transposed into the LDS A-tile.
// Phase 3: r12 mlp (v_e pass from A, then x pass, then W2 pass) -> out.
// ve / eids / deg never touch HBM.
__global__ __launch_bounds__(512) void fused2_k(const int* __restrict__ bbuf,
                                                const int* __restrict__ blkoff,
                                                const vfloat4* __restrict__ ea4,
                                                const float* __restrict__ x,
                                                const int* __restrict__ batch,
                                                const float* __restrict__ W1,
                                                const float* __restrict__ W2,
                                                const float* __restrict__ b2,
                                                const float* __restrict__ U1,
                                                float* __restrict__ out) {
    __shared__ int eids_l[BN * CAP];    // 32 KB; reused as Wb (16 KB) in phase 3
    __shared__ float A[64 * LDA];       // 33.8 KB
    __shared__ int cnt[BN];
    __shared__ int lo_s[NBLK_A], hi_s[NBLK_A];
    __shared__ int segoff[NBLK_A + 1];
    float* Wb = (float*)eids_l;

    const int b = blockIdx.x;
    const int tid = threadIdx.x;
    const int n0 = b * BN;

    if (tid < BN) cnt[tid] = 0;
    for (int i = tid; i < NBLK_A; i += 512) {
        lo_s[i] = blkoff[i * (NBKT + 1) + b];
        hi_s[i] = blkoff[i * (NBKT + 1) + b + 1];
    }
    __syncthreads();

    // exclusive scan of 196 segment lengths by wave 0 (4 per lane)
    if (tid < 64) {
        const int base = tid * 4;
        int a0 = 0, a1 = 0, a2 = 0, a3 = 0;
        if (base < NBLK_A) {
            a0 = hi_s[base + 0] - lo_s[base + 0];
            a1 = hi_s[base + 1] - lo_s[base + 1];
            a2 = hi_s[base + 2] - lo_s[base + 2];
            a3 = hi_s[base + 3] - lo_s[base + 3];
        }
        const int sum = a0 + a1 + a2 + a3;
        int run = sum;
        #pragma unroll
        for (int m = 1; m < 64; m <<= 1) {
            int v = __shfl_up(run, m, 64);
            if (tid >= m) run += v;
        }
        const int excl = run - sum;
        if (base < NBLK_A) {
            segoff[base + 0] = excl;
            segoff[base + 1] = excl + a0;
            segoff[base + 2] = excl + a0 + a1;
            segoff[base + 3] = excl + a0 + a1 + a2;
        }
        if (tid == 63) segoff[NBLK_A] = run;
    }
    __syncthreads();

    // ---- phase 1: rank + place into LDS (no src re-read: nl packed in bbuf) ----
    const int total = segoff[NBLK_A];
    for (int i = tid; i < total; i += 512) {
        int lo2 = 0, hi2 = NBLK_A;
        while (lo2 + 1 < hi2) {
            int mid = (lo2 + hi2) >> 1;
            if (segoff[mid] <= i) lo2 = mid; else hi2 = mid;
        }
        const int idx = i - segoff[lo2] + lo_s[lo2];
        const int v = bbuf[lo2 * EB + idx];
        const int e = v & 0xFFFFF;
        const int nl = v >> 20;
        const int rank = atomicAdd(&cnt[nl], 1);
        if (rank < CAP) eids_l[nl * CAP + rank] = e;
    }
    __syncthreads();

    // ---- phase 2: gather-reduce, v_e^T -> A-tile (8 waves x 16 nodes) ----
    {
        const int wave = tid >> 6, lane = tid & 63;
        const int chunk = lane & 15, slot = lane >> 4;
        const vfloat4 vzero = {0.f, 0.f, 0.f, 0.f};
        for (int m = 0; m < 16; ++m) {
            const int nl = wave * 16 + m;
            const int n = n0 + nl;
            if (n >= NN) break;
            const int deg = min(cnt[nl], CAP);
            const int* ebase = eids_l + nl * CAP;

            vfloat4 acc = vzero;
            if (deg > 0) {
                const int dm1 = deg - 1;
                int e[8];
                #pragma unroll
                for (int r = 0; r < 8; ++r) {
                    int j = slot + r * 4;
                    e[r] = ebase[j < dm1 ? j : dm1];
                }
                #pragma unroll
                for (int r = 0; r < 8; ++r) {
                    vfloat4 v = __builtin_nontemporal_load(&ea4[(size_t)e[r] * 16 + chunk]);
                    acc += (slot + r * 4 < deg) ? v : vzero;
                }
                for (int j = 32 + slot; j < deg; j += 4) {   // rare tail
                    int ee = ebase[j];
                    vfloat4 v = __builtin_nontemporal_load(&ea4[(size_t)ee * 16 + chunk]);
                    acc += v;
                }
            }
            #pragma unroll
            for (int mm = 16; mm <= 32; mm <<= 1) {
                acc.x += __shfl_xor(acc.x, mm, 64);
                acc.y += __shfl_xor(acc.y, mm, 64);
                acc.z += __shfl_xor(acc.z, mm, 64);
                acc.w += __shfl_xor(acc.w, mm, 64);
            }
            if (slot == 0) {
                const float rs = 1.0f / fmaxf((float)deg, 1.0f);
                A[(chunk * 4 + 0) * LDA + nl] = acc.x * rs;
                A[(chunk * 4 + 1) * LDA + nl] = acc.y * rs;
                A[(chunk * 4 + 2) * LDA + nl] = acc.z * rs;
                A[(chunk * 4 + 3) * LDA + nl] = acc.w * rs;
            }
        }
    }
    __syncthreads();   // A holds v_e^T; eids_l reads done -> region becomes Wb

    // ---- phase 3: MLP (r12 512-thread shape) ----
    const int c = tid & 15;
    const int rb = tid >> 4;          // 0..31
    const int DG = c * 4;
    const int NG = rb * 4;

    float acc[4][4];

    // stage Wb = W1[64:128] (v_e block); init acc from U1
    #pragma unroll
    for (int it = 0; it < 2; ++it) {
        int r = rb + it * 32;
        *(float4*)&Wb[r * 64 + c * 4] = *(const float4*)&W1[(size_t)(64 + r) * DIM + c * 4];
    }
    #pragma unroll
    for (int i = 0; i < 4; ++i) {
        int n = n0 + NG + i;
        int bb = (n < NN) ? batch[n] : 0;
        const float4 uv = *(const float4*)&U1[bb * DIM + DG];
        acc[i][0] = uv.x; acc[i][1] = uv.y; acc[i][2] = uv.z; acc[i][3] = uv.w;
    }
    __syncthreads();

    // pass 1: v_e @ W1[64:128]
    gemm4(acc, A, Wb, NG, DG);
    __syncthreads();

    // pass 2: x @ W1[0:64]
    #pragma unroll
    for (int it = 0; it < 4; ++it) {
        int r = rb + it * 32;
        int n = n0 + r;
        float4 v = make_float4(0.f, 0.f, 0.f, 0.f);
        if (n < NN) v = *(const float4*)&x[(size_t)n * DIM + c * 4];
        A[(c * 4 + 0) * LDA + r] = v.x;
        A[(c * 4 + 1) * LDA + r] = v.y;
        A[(c * 4 + 2) * LDA + r] = v.z;
        A[(c * 4 + 3) * LDA + r] = v.w;
    }
    #pragma unroll
    for (int it = 0; it < 2; ++it) {
        int r = rb + it * 32;
        *(float4*)&Wb[r * 64 + c * 4] = *(const float4*)&W1[(size_t)r * DIM + c * 4];
    }
    __syncthreads();
    gemm4(acc, A, Wb, NG, DG);

    #pragma unroll
    for (int i = 0; i < 4; ++i)
        #pragma unroll
        for (int j = 0; j < 4; ++j)
            acc[i][j] = fmaxf(acc[i][j], 0.f);

    __syncthreads();

    // layer 2: h @ W2
    #pragma unroll
    for (int j = 0; j < 4; ++j) {
        float4 h = make_float4(acc[0][j], acc[1][j], acc[2][j], acc[3][j]);
        *(float4*)&A[(DG + j) * LDA + NG] = h;
    }
    #pragma unroll
    for (int it = 0; it < 2; ++it) {
        int r = rb + it * 32;
        *(float4*)&Wb[r * 64 + c * 4] = *(const float4*)&W2[(size_t)r * DIM + c * 4];
    }
    __syncthreads();

    {
        const float4 bv = *(const float4*)&b2[DG];
        #pragma unroll
        for (int i = 0; i < 4; ++i) {
            acc[i][0] = bv.x; acc[i][1] = bv.y; acc[i][2] = bv.z; acc[i][3] = bv.w;
        }
    }
    gemm4(acc, A, Wb, NG, DG);

    #pragma unroll
    for (int i = 0; i < 4; ++i) {
        int n = n0 + NG + i;
        if (n < NN) {
            float4 o = make_float4(acc[i][0], acc[i][1], acc[i][2], acc[i][3]);
            *(float4*)&out[(size_t)n * DIM + DG] = o;
        }
    }
}

extern "C" void kernel_launch(void* const* d_in, const int* in_sizes, int n_in,
                              void* d_out, int out_size, void* d_ws, size_t ws_size,
                              hipStream_t stream)
{
    const float* x     = (const float*)d_in[0];
    const int*   eidx  = (const int*)d_in[1];    // [2,E], row 0 = src
    const float* ea    = (const float*)d_in[2];
    const float* u     = (const float*)d_in[3];
    const int*   batch = (const int*)d_in[4];
    const float* W1    = (const float*)d_in[5];
    const float* b1    = (const float*)d_in[6];
    const float* W2    = (const float*)d_in[7];
    const float* b2    = (const float*)d_in[8];
    float* out = (float*)d_out;

    float* U1     = (float*)d_ws;                      // NB*DIM floats
    int*   bbuf   = (int*)(U1 + NB * DIM);             // NBLK_A*EB ints
    int*   blkoff = bbuf + (size_t)NBLK_A * EB;        // NBLK_A*(NBKT+1) ints

    bucketA_k<<<NBLK_A, 1024, 0, stream>>>(eidx, bbuf, blkoff, u, W1, b1, U1);
    fused2_k<<<NBKT, 512, 0, stream>>>(bbuf, blkoff, (const vfloat4*)ea,
                                       x, batch, W1, W2, b2, U1, out);
}